// Round 6
// baseline (580.378 us; speedup 1.0000x reference)
//
#include <hip/hip_runtime.h>

#define NODES 100000
#define EDGES 1600000
#define FEATS 128
#define NCLS  16

// bucket = 64 consecutive dst nodes
#define BSH    6
#define BNODES 64
#define NB     ((NODES + BNODES - 1) / BNODES)   // 1563
#define CHUNK  8192
#define NBLK   ((EDGES + CHUNK - 1) / CHUNK)     // 196
#define NHIST  (NB * NBLK)                       // 306348
#define BCAP   2048                              // per-bucket LDS sort capacity
#define WPAD   136                               // padded LDS row (u16) -> 2-way banks only

typedef unsigned int  u32;
typedef unsigned short u16;
typedef __attribute__((ext_vector_type(8))) short short8;
typedef __attribute__((ext_vector_type(4))) float f32x4;

__device__ __forceinline__ float b2f(u16 v){ return __uint_as_float(((u32)v)<<16); }
__device__ __forceinline__ u16 f2b(float f){
  u32 u = __float_as_uint(f);
  u += 0x7fffu + ((u>>16)&1u);   // RNE
  return (u16)(u>>16);
}
__device__ __forceinline__ float blo(u32 p){ return __uint_as_float(p<<16); }
__device__ __forceinline__ float bhi(u32 p){ return __uint_as_float(p & 0xffff0000u); }

// ---------------- phase A: per-chunk bucket histogram ----------------

__global__ __launch_bounds__(256) void pA_k(const int* __restrict__ dst,
                                            int* __restrict__ gh, int E){
  __shared__ int hist[NB];
  int t = threadIdx.x, blk = blockIdx.x;
  for (int j = t; j < NB; j += 256) hist[j] = 0;
  __syncthreads();
  int e0 = blk*CHUNK, e1 = e0 + CHUNK; if (e1 > E) e1 = E;
  for (int e = e0 + t; e < e1; e += 256) atomicAdd(&hist[dst[e] >> BSH], 1);
  __syncthreads();
  for (int j = t; j < NB; j += 256) gh[j*NBLK + blk] = hist[j];
}

// ---------------- phase B: exclusive scan of gh ----------------

__global__ __launch_bounds__(256) void scan1_k(const int* __restrict__ in, int* __restrict__ out,
                                               int* __restrict__ bsum, int n){
  __shared__ int sh[256];
  int t = threadIdx.x;
  int base = blockIdx.x*2048 + t*8;
  int v[8]; int s = 0;
  #pragma unroll
  for (int j=0;j<8;++j) v[j] = (base+j < n) ? in[base+j] : 0;
  #pragma unroll
  for (int j=0;j<8;++j){ int tmp = v[j]; v[j] = s; s += tmp; }
  sh[t] = s; __syncthreads();
  for (int off=1; off<256; off<<=1){
    int x = (t>=off) ? sh[t-off] : 0;
    __syncthreads();
    sh[t] += x;
    __syncthreads();
  }
  int excl = sh[t] - s;
  #pragma unroll
  for (int j=0;j<8;++j) if (base+j < n) out[base+j] = excl + v[j];
  if (t == 255) bsum[blockIdx.x] = sh[255];
}

__global__ __launch_bounds__(256) void scan2_k(const int* __restrict__ bsum,
                                               int* __restrict__ boff, int nb){
  __shared__ int sh[256];
  int t = threadIdx.x;
  int v = (t < nb) ? bsum[t] : 0;
  sh[t] = v; __syncthreads();
  for (int off=1; off<256; off<<=1){
    int x = (t>=off) ? sh[t-off] : 0;
    __syncthreads();
    sh[t] += x;
    __syncthreads();
  }
  if (t < nb) boff[t] = sh[t] - v;
}

__global__ void scan3_k(int* __restrict__ gscan, const int* __restrict__ boff,
                        int* __restrict__ bstart, int n){
  int i = blockIdx.x*256 + threadIdx.x;
  if (i < n){
    int v = gscan[i] + boff[i>>11];
    gscan[i] = v;
    if (i % NBLK == 0) bstart[i / NBLK] = v;
    if (i == 0) bstart[NB] = EDGES;
  }
}

// ---------------- phase C: LDS counting sort, then streamed coalesced write ----------------

__global__ __launch_bounds__(256) void pC_k(const int* __restrict__ src,
    const int* __restrict__ dst, const int* __restrict__ gscan,
    u32* __restrict__ elist, int E){
  __shared__ int A[NB];        // hist -> excl -> delta
  __shared__ int B[NB];        // running local position
  __shared__ int sp[256];
  __shared__ u32 pay[CHUNK];
  __shared__ u16 bkt[CHUNK];
  int t = threadIdx.x, blk = blockIdx.x;
  for (int j = t; j < NB; j += 256) A[j] = 0;
  __syncthreads();
  int e0 = blk*CHUNK, e1 = e0 + CHUNK; if (e1 > E) e1 = E;
  int cnt = e1 - e0;
  for (int e = e0 + t; e < e1; e += 256) atomicAdd(&A[dst[e] >> BSH], 1);
  __syncthreads();
  {
    int base = t*7;
    int cv[7]; int s = 0;
    #pragma unroll
    for (int j=0;j<7;++j){ int idx = base+j; cv[j] = (idx < NB) ? A[idx] : 0; s += cv[j]; }
    sp[t] = s; __syncthreads();
    for (int off=1; off<256; off<<=1){
      int x = (t>=off) ? sp[t-off] : 0;
      __syncthreads();
      sp[t] += x;
      __syncthreads();
    }
    int run = sp[t] - s;
    #pragma unroll
    for (int j=0;j<7;++j){
      int idx = base+j;
      if (idx < NB){ A[idx] = run; B[idx] = run; run += cv[j]; }
    }
  }
  __syncthreads();
  for (int j = t; j < NB; j += 256) A[j] = gscan[j*NBLK + blk] - A[j];
  __syncthreads();
  for (int e = e0 + t; e < e1; e += 256){
    int d = dst[e];
    int b = d >> BSH;
    u32 w = ((u32)(d & (BNODES-1)) << 17) | (u32)src[e];
    int r = atomicAdd(&B[b], 1);
    pay[r] = w; bkt[r] = (u16)b;
  }
  __syncthreads();
  for (int i = t; i < cnt; i += 256){
    int b = bkt[i];
    elist[i + A[b]] = pay[i];
  }
}

// ---------------- per-bucket counting sort (in place) + degrees ----------------

__global__ __launch_bounds__(256) void csr_k(u32* __restrict__ elist,
    const int* __restrict__ bstart, int* __restrict__ offs, int* __restrict__ degs,
    float* __restrict__ invd, int M){
  __shared__ int hist[BNODES];
  __shared__ int pos[BNODES];
  __shared__ u32 buf[BCAP];
  __shared__ u32 buf2[BCAP];
  int b = blockIdx.x, t = threadIdx.x;
  if (t < BNODES) hist[t] = 0;
  __syncthreads();
  int s0 = bstart[b];
  int cnt = bstart[b+1] - s0; if (cnt > BCAP) cnt = BCAP;
  u32* el = elist + s0;
  for (int e = t; e < cnt; e += 256){
    u32 w = el[e];
    buf[e] = w;
    atomicAdd(&hist[w>>17], 1);
  }
  __syncthreads();
  if (t < BNODES){
    int v = hist[t];
    int s = v;
    for (int off = 1; off < BNODES; off <<= 1){
      int x = __shfl_up(s, off);
      if (t >= off) s += x;
    }
    int excl = s - v;
    pos[t] = excl;
    int node = b*BNODES + t;
    if (node < M){
      offs[node] = s0 + excl;
      degs[node] = v;
      invd[node] = 1.f / fmaxf((float)v, 1.f);
    }
  }
  __syncthreads();
  for (int e = t; e < cnt; e += 256){
    u32 w = buf[e];
    int p = atomicAdd(&pos[w>>17], 1);
    buf2[p] = w & 0x1FFFFu;
  }
  __syncthreads();
  for (int e = t; e < cnt; e += 256) el[e] = buf2[e];
}

// ---------------- dtype conversion ----------------

__global__ void convf_k(const float* __restrict__ in, u16* __restrict__ o, int n4){
  int i = blockIdx.x*256 + threadIdx.x;
  if (i < n4){
    float4 x = ((const float4*)in)[i];
    ushort4 r;
    r.x = f2b(x.x); r.y = f2b(x.y); r.z = f2b(x.z); r.w = f2b(x.w);
    ((ushort4*)o)[i] = r;
  }
}

__global__ void convw_k(const float* __restrict__ W, u16* __restrict__ Wt, int Kd, int Nd){
  int i = blockIdx.x*256 + threadIdx.x;
  if (i < Kd*Nd){
    int k = i / Nd, nn = i - k*Nd;
    Wt[nn*Kd + k] = f2b(W[i]);
  }
}

// ---------------- fused layer kernel (layers 0..2) ----------------
// block = 1 dst bucket (64 nodes, 4 waves x 16 nodes).
// phase 1: wave gathers neighbor rows (uint4: 16 lanes = full 256B row, 4 rows/load),
//          z = (1+eps)*h[v] + inv_deg * sum h[src]  -> LDS z-tile (bf16, padded rows)
// phase 2: per-wave 16x128 @ 128x128 GEMM from LDS (W staged, padded), relu+bias, store.
// zero-row trick: h has a row NODES of zeros; padded edges use src=NODES.

__global__ __launch_bounds__(256) void fused_k(const uint4* __restrict__ h4,
    const u32* __restrict__ el, const int* __restrict__ offs,
    const int* __restrict__ degs, const float* __restrict__ invd,
    const u16* __restrict__ Wt, const float* __restrict__ bias,
    const float* __restrict__ epsv, int ei, u16* __restrict__ hout, int M){
  __shared__ __align__(16) u16 Wl[128*WPAD];      // 34 KB
  __shared__ __align__(16) u16 zb[4*16*WPAD];     // 17 KB
  int t = threadIdx.x;
  int lane = t & 63;
  int wave = t >> 6;
  int b = blockIdx.x;
  int c = lane & 15;          // column group: feats 8c..8c+7
  int g = lane >> 4;          // row group within a 4-row load

  // stage W into padded LDS
  for (int i = t; i < 128*16; i += 256){
    int row = i >> 4, c8 = i & 15;
    *(uint4*)&Wl[row*WPAD + c8*8] = ((const uint4*)Wt)[i];
  }
  __syncthreads();

  float e1s = 1.f + epsv[ei];
  u16* zw = zb + wave*16*WPAD;

  // ---- phase 1: gather + aggregate 16 nodes ----
  for (int i = 0; i < 16; ++i){
    int n = b*64 + wave*16 + i;
    int start = 0, deg = 0; float inv = 0.f;
    if (n < M){ start = offs[n]; deg = degs[n]; inv = invd[n]; }
    float a0=0.f,a1=0.f,a2=0.f,a3=0.f,a4=0.f,a5=0.f,a6=0.f,a7=0.f;
    for (int e0 = 0; e0 < deg; e0 += 64){
      int my = (e0 + lane < deg) ? (int)el[start + e0 + lane] : NODES;
      int lim = deg - e0; if (lim > 64) lim = 64;
      for (int sub = 0; sub < lim; sub += 16){
        int s0 = __shfl(my, sub      + g);
        int s1 = __shfl(my, sub + 4  + g);
        int s2 = __shfl(my, sub + 8  + g);
        int s3 = __shfl(my, sub + 12 + g);
        uint4 p0 = h4[(size_t)s0*16 + c];
        uint4 p1 = h4[(size_t)s1*16 + c];
        uint4 p2 = h4[(size_t)s2*16 + c];
        uint4 p3 = h4[(size_t)s3*16 + c];
        a0 += blo(p0.x)+blo(p1.x)+blo(p2.x)+blo(p3.x);
        a1 += bhi(p0.x)+bhi(p1.x)+bhi(p2.x)+bhi(p3.x);
        a2 += blo(p0.y)+blo(p1.y)+blo(p2.y)+blo(p3.y);
        a3 += bhi(p0.y)+bhi(p1.y)+bhi(p2.y)+bhi(p3.y);
        a4 += blo(p0.z)+blo(p1.z)+blo(p2.z)+blo(p3.z);
        a5 += bhi(p0.z)+bhi(p1.z)+bhi(p2.z)+bhi(p3.z);
        a6 += blo(p0.w)+blo(p1.w)+blo(p2.w)+blo(p3.w);
        a7 += bhi(p0.w)+bhi(p1.w)+bhi(p2.w)+bhi(p3.w);
      }
    }
    a0 += __shfl_xor(a0,16); a0 += __shfl_xor(a0,32);
    a1 += __shfl_xor(a1,16); a1 += __shfl_xor(a1,32);
    a2 += __shfl_xor(a2,16); a2 += __shfl_xor(a2,32);
    a3 += __shfl_xor(a3,16); a3 += __shfl_xor(a3,32);
    a4 += __shfl_xor(a4,16); a4 += __shfl_xor(a4,32);
    a5 += __shfl_xor(a5,16); a5 += __shfl_xor(a5,32);
    a6 += __shfl_xor(a6,16); a6 += __shfl_xor(a6,32);
    a7 += __shfl_xor(a7,16); a7 += __shfl_xor(a7,32);
    int nS = (n < M) ? n : NODES;
    uint4 pv = h4[(size_t)nS*16 + c];
    float z0 = e1s*blo(pv.x) + inv*a0;
    float z1 = e1s*bhi(pv.x) + inv*a1;
    float z2 = e1s*blo(pv.y) + inv*a2;
    float z3 = e1s*bhi(pv.y) + inv*a3;
    float z4 = e1s*blo(pv.z) + inv*a4;
    float z5 = e1s*bhi(pv.z) + inv*a5;
    float z6 = e1s*blo(pv.w) + inv*a6;
    float z7 = e1s*bhi(pv.w) + inv*a7;
    if (g == 0){
      uint4 zp;
      zp.x = (u32)f2b(z0) | ((u32)f2b(z1) << 16);
      zp.y = (u32)f2b(z2) | ((u32)f2b(z3) << 16);
      zp.z = (u32)f2b(z4) | ((u32)f2b(z5) << 16);
      zp.w = (u32)f2b(z6) | ((u32)f2b(z7) << 16);
      *(uint4*)&zw[i*WPAD + c*8] = zp;
    }
  }

  // ---- phase 2: z(16x128) @ W(128x128), relu+bias ----
  int m = lane & 15;
  int quad = lane >> 4;
  f32x4 acc[8];
  #pragma unroll
  for (int j=0;j<8;++j) acc[j] = (f32x4){0.f,0.f,0.f,0.f};
  #pragma unroll
  for (int kk = 0; kk < 128; kk += 32){
    short8 af = *(const short8*)&zw[m*WPAD + kk + quad*8];
    #pragma unroll
    for (int j=0;j<8;++j){
      short8 bf = *(const short8*)&Wl[(j*16 + m)*WPAD + kk + quad*8];
      acc[j] = __builtin_amdgcn_mfma_f32_16x16x32_bf16(af, bf, acc[j], 0, 0, 0);
    }
  }
  #pragma unroll
  for (int j=0;j<8;++j){
    float bj = bias[j*16 + m];
    #pragma unroll
    for (int r=0;r<4;++r){
      int gnode = b*64 + wave*16 + quad*4 + r;    // C/D: row = quad*4 + r, col = m
      if (gnode < M){
        float o = fmaxf(acc[j][r] + bj, 0.f);
        hout[(size_t)gnode*FEATS + j*16 + m] = f2b(o);
      }
    }
  }
}

// ---------------- GEMM (layer 3 only): y = h@W3, N=16 ----------------

template<int NT>
__global__ __launch_bounds__(256) void gemm_k(const u16* __restrict__ h,
                                              const u16* __restrict__ Wt,
                                              u16* __restrict__ y, int M){
  const int K = FEATS;
  const int N = NT*16;
  int lane = threadIdx.x & 63;
  int wave = threadIdx.x >> 6;
  int m    = lane & 15;
  int quad = lane >> 4;
  int row0 = (blockIdx.x*4 + wave)*16;
  if (row0 >= M) return;
  int rowA = row0 + m; if (rowA > M-1) rowA = M-1;
  const u16* pa = h + (size_t)rowA*K + quad*8;

  f32x4 acc[NT];
  #pragma unroll
  for (int j=0;j<NT;++j) acc[j] = (f32x4){0.f,0.f,0.f,0.f};

  #pragma unroll
  for (int kk=0; kk<K; kk+=32){
    short8 a = *(const short8*)(pa + kk);
    #pragma unroll
    for (int j=0;j<NT;++j){
      short8 b = *(const short8*)(Wt + (size_t)(j*16 + m)*K + kk + quad*8);
      acc[j] = __builtin_amdgcn_mfma_f32_16x16x32_bf16(a, b, acc[j], 0, 0, 0);
    }
  }

  #pragma unroll
  for (int j=0;j<NT;++j){
    #pragma unroll
    for (int r=0;r<4;++r){
      int row = row0 + quad*4 + r;
      if (row < M) y[(size_t)row*N + j*16 + m] = f2b(acc[j][r]);
    }
  }
}

// ---------------- final 16-feat aggregation, f32 out, no relu ----------------
// one wave per node; uint2 = 4 feats/lane, 4 lanes/row, 16 edges per load round.

__global__ __launch_bounds__(256) void aggF2_k(const uint2* __restrict__ y2,
    const u32* __restrict__ el, const int* __restrict__ offs,
    const int* __restrict__ degs, const float* __restrict__ invd,
    const float* __restrict__ bias, const float* __restrict__ epsv,
    float* __restrict__ out, int M){
  int lane = threadIdx.x & 63;
  int v = blockIdx.x*4 + (threadIdx.x >> 6);
  if (v >= M) return;
  int c = lane & 3;           // feats 4c..4c+3
  int g = lane >> 2;          // 16 edges in parallel
  int start = offs[v], deg = degs[v];
  float a0=0.f,a1=0.f,a2=0.f,a3=0.f;
  for (int e0 = 0; e0 < deg; e0 += 64){
    int my = (e0 + lane < deg) ? (int)el[start + e0 + lane] : NODES;
    int lim = deg - e0; if (lim > 64) lim = 64;
    for (int sub = 0; sub < lim; sub += 16){
      int s = __shfl(my, sub + g);
      uint2 p = y2[(size_t)s*4 + c];
      a0 += blo(p.x); a1 += bhi(p.x); a2 += blo(p.y); a3 += bhi(p.y);
    }
  }
  a0 += __shfl_xor(a0,4); a0 += __shfl_xor(a0,8); a0 += __shfl_xor(a0,16); a0 += __shfl_xor(a0,32);
  a1 += __shfl_xor(a1,4); a1 += __shfl_xor(a1,8); a1 += __shfl_xor(a1,16); a1 += __shfl_xor(a1,32);
  a2 += __shfl_xor(a2,4); a2 += __shfl_xor(a2,8); a2 += __shfl_xor(a2,16); a2 += __shfl_xor(a2,32);
  a3 += __shfl_xor(a3,4); a3 += __shfl_xor(a3,8); a3 += __shfl_xor(a3,16); a3 += __shfl_xor(a3,32);
  if (g == 0){
    uint2 pv = y2[(size_t)v*4 + c];
    float4 bi = ((const float4*)bias)[c];
    float inv = invd[v], e1s = 1.f + epsv[3];
    float4 o;
    o.x = e1s*blo(pv.x) + inv*a0 + bi.x;
    o.y = e1s*bhi(pv.x) + inv*a1 + bi.y;
    o.z = e1s*blo(pv.y) + inv*a2 + bi.z;
    o.w = e1s*bhi(pv.y) + inv*a3 + bi.w;
    ((float4*)out)[(size_t)v*4 + c] = o;
  }
}

// ---------------- launch ----------------

extern "C" void kernel_launch(void* const* d_in, const int* in_sizes, int n_in,
                              void* d_out, int out_size, void* d_ws, size_t ws_size,
                              hipStream_t stream){
  const float* feats = (const float*)d_in[0];
  const int*   src   = (const int*)d_in[1];
  const int*   dst   = (const int*)d_in[2];
  const float* W0 = (const float*)d_in[3];  const float* b0 = (const float*)d_in[4];
  const float* W1 = (const float*)d_in[5];  const float* b1 = (const float*)d_in[6];
  const float* W2 = (const float*)d_in[7];  const float* b2 = (const float*)d_in[8];
  const float* W3 = (const float*)d_in[9];  const float* b3 = (const float*)d_in[10];
  const float* eps = (const float*)d_in[11];

  char* w = (char*)d_ws;
  auto alloc = [&](size_t bytes)->char*{
    char* p = w; w += (bytes + 255) & ~(size_t)255; return p;
  };
  int*  gh    = (int*)alloc(sizeof(int)*NHIST);
  int*  gscan = (int*)alloc(sizeof(int)*NHIST);
  int*  bsum  = (int*)alloc(sizeof(int)*256);
  int*  boff  = (int*)alloc(sizeof(int)*256);
  int*  bstart= (int*)alloc(sizeof(int)*(NB+1));
  int*  offs  = (int*)alloc(sizeof(int)*NODES);
  int*  degs  = (int*)alloc(sizeof(int)*NODES);
  float* invd = (float*)alloc(sizeof(float)*NODES);
  u32*  elist = (u32*)alloc(sizeof(u32)*EDGES);
  u16*  hb    = (u16*)alloc(sizeof(u16)*(size_t)(NODES+1)*FEATS);
  u16*  h2    = (u16*)alloc(sizeof(u16)*(size_t)(NODES+1)*FEATS);
  u16*  yb    = (u16*)alloc(sizeof(u16)*(size_t)(NODES+1)*NCLS);
  u16*  Wt0   = (u16*)alloc(sizeof(u16)*128*128);
  u16*  Wt1   = (u16*)alloc(sizeof(u16)*128*128);
  u16*  Wt2   = (u16*)alloc(sizeof(u16)*128*128);
  u16*  Wt3   = (u16*)alloc(sizeof(u16)*16*128);

  // zero rows for padded-edge trick (src = NODES reads zeros)
  hipMemsetAsync(hb + (size_t)NODES*FEATS, 0, FEATS*sizeof(u16), stream);
  hipMemsetAsync(h2 + (size_t)NODES*FEATS, 0, FEATS*sizeof(u16), stream);
  hipMemsetAsync(yb + (size_t)NODES*NCLS,  0, NCLS*sizeof(u16),  stream);

  // ---- deterministic 3-phase partition -> dense bucketed elist ----
  pA_k<<<NBLK, 256, 0, stream>>>(dst, gh, EDGES);
  int snb = (NHIST + 2047)/2048;                 // 150 <= 256
  scan1_k<<<snb, 256, 0, stream>>>(gh, gscan, bsum, NHIST);
  scan2_k<<<1, 256, 0, stream>>>(bsum, boff, snb);
  scan3_k<<<(NHIST+255)/256, 256, 0, stream>>>(gscan, boff, bstart, NHIST);
  pC_k<<<NBLK, 256, 0, stream>>>(src, dst, gscan, elist, EDGES);
  csr_k<<<NB, 256, 0, stream>>>(elist, bstart, offs, degs, invd, NODES);

  // ---- convert inputs to bf16 ----
  convf_k<<<((NODES*FEATS/4)+255)/256, 256, 0, stream>>>(feats, hb, NODES*FEATS/4);
  convw_k<<<(128*128+255)/256, 256, 0, stream>>>(W0, Wt0, 128, 128);
  convw_k<<<(128*128+255)/256, 256, 0, stream>>>(W1, Wt1, 128, 128);
  convw_k<<<(128*128+255)/256, 256, 0, stream>>>(W2, Wt2, 128, 128);
  convw_k<<<(128*16 +255)/256, 256, 0, stream>>>(W3, Wt3, 128, 16);

  // layers 0..2 fused: h' = relu( ((1+eps)h + mean_agg(h)) @ W + b )
  fused_k<<<NB, 256, 0, stream>>>((const uint4*)hb, elist, offs, degs, invd, Wt0, b0, eps, 0, h2, NODES);
  fused_k<<<NB, 256, 0, stream>>>((const uint4*)h2, elist, offs, degs, invd, Wt1, b1, eps, 1, hb, NODES);
  fused_k<<<NB, 256, 0, stream>>>((const uint4*)hb, elist, offs, degs, invd, Wt2, b2, eps, 2, h2, NODES);

  // layer 3: y = h@W3 (N=16); out = (1+eps)y + mean_agg(y) + b  (f32, no relu)
  gemm_k<1><<<(NODES+63)/64, 256, 0, stream>>>(h2, Wt3, yb, NODES);
  aggF2_k<<<(NODES+3)/4, 256, 0, stream>>>((const uint2*)yb, elist, offs, degs, invd, b3, eps, (float*)d_out, NODES);
}